// Round 10
// baseline (76.849 us; speedup 1.0000x reference)
//
#include <hip/hip_runtime.h>
#include <hip/hip_bf16.h>
#include <math.h>

// Problem constants
#define BB   256
#define INW  512
#define HH   1024
#define OUTW 512
#define SS   512
#define WD   256
#define P_READ  262
#define P_WRITE 774
#define RW_LD   1056   // 272 (read pad) + 784 (write pad)
#define W_OFF   272

typedef __attribute__((ext_vector_type(8))) short bf16x8;
typedef __attribute__((ext_vector_type(4))) short bf16x4;
typedef __attribute__((ext_vector_type(4))) float f32x4;

__device__ __forceinline__ float sigmoidf(float x) { return 1.f / (1.f + expf(-x)); }
__device__ __forceinline__ float softplusf(float x) { return (x > 20.f) ? x : log1pf(expf(x)); }
__device__ __forceinline__ float b2f(short s) {
    union { float f; unsigned u; } c; c.u = ((unsigned)(unsigned short)s) << 16; return c.f;
}
__device__ __forceinline__ unsigned short f2b(float f) {
    union { float f; unsigned u; } c; c.f = f;
    return (unsigned short)((c.u + 0x7FFFu + ((c.u >> 16) & 1u)) >> 16);
}
__device__ __forceinline__ void st_bf4(__hip_bfloat16* d, float a, float b, float c, float e) {
    ushort4 u; u.x = f2b(a); u.y = f2b(b); u.z = f2b(c); u.w = f2b(e);
    *reinterpret_cast<ushort4*>(d) = u;
}

// conversion segment sizes (all multiples of 4)
#define N_WIH (3072*512)
#define N_WRW (RW_LD*1024)
#define N_WO  (512*1280)
#define N_X   (256*512)
#define N_MB  (512*256)
#define N_BIA 3072
#define N_BRW RW_LD
#define N_TOT (N_WIH+N_WRW+N_WO+N_X+N_MB+N_BIA+N_BRW)
#define NB_CVT ((N_TOT/4 + 255) / 256)

// ================= K1: convert/pack (4-wide) + biases =================
__global__ __launch_bounds__(256)
void convert_all(const float* __restrict__ W_ih, const float* __restrict__ b_ih,
                 const float* __restrict__ b_hh,
                 const float* __restrict__ W_read, const float* __restrict__ b_read,
                 const float* __restrict__ W_write, const float* __restrict__ b_write,
                 const float* __restrict__ W_out, const float* __restrict__ x,
                 const float* __restrict__ mem,
                 __hip_bfloat16* __restrict__ Wih_c, __hip_bfloat16* __restrict__ Wrw_p,
                 __hip_bfloat16* __restrict__ Wo_b, __hip_bfloat16* __restrict__ x_b,
                 __hip_bfloat16* __restrict__ mem_b,
                 float* __restrict__ bias_c, float* __restrict__ bias_rw)
{
    long i = ((long)blockIdx.x * 256 + threadIdx.x) * 4;
    if (i >= N_TOT) return;
    if (i < N_WIH) {
        int r = (int)(i >> 9), c = (int)(i & 511);
        int sr = r < 1024 ? r : r + 1024;    // skip f-gate rows
        float4 v = *reinterpret_cast<const float4*>(W_ih + (size_t)sr * 768 + c);
        st_bf4(Wih_c + i, v.x, v.y, v.z, v.w);
        return;
    }
    i -= N_WIH;
    if (i < N_WRW) {
        int r = (int)(i >> 10), c = (int)(i & 1023);
        float4 v = make_float4(0.f, 0.f, 0.f, 0.f);
        if (r < W_OFF) { if (r < P_READ) v = *reinterpret_cast<const float4*>(W_read + (size_t)r * 1024 + c); }
        else { int wr = r - W_OFF; if (wr < P_WRITE) v = *reinterpret_cast<const float4*>(W_write + (size_t)wr * 1024 + c); }
        st_bf4(Wrw_p + i, v.x, v.y, v.z, v.w);
        return;
    }
    i -= N_WRW;
    if (i < N_WO) {
        float4 v = *reinterpret_cast<const float4*>(W_out + i);
        st_bf4(Wo_b + i, v.x, v.y, v.z, v.w);
        return;
    }
    i -= N_WO;
    if (i < N_X) {
        float4 v = *reinterpret_cast<const float4*>(x + i);
        st_bf4(x_b + i, v.x, v.y, v.z, v.w);
        return;
    }
    i -= N_X;
    if (i < N_MB) {
        float4 v = *reinterpret_cast<const float4*>(mem + i);
        st_bf4(mem_b + i, v.x, v.y, v.z, v.w);
        return;
    }
    i -= N_MB;
    if (i < N_BIA) {
        #pragma unroll
        for (int u = 0; u < 4; ++u) {
            long r = i + u;
            long sr = r < 1024 ? r : r + 1024;
            bias_c[r] = b_ih[sr] + b_hh[sr];
        }
        return;
    }
    i -= N_BIA;
    {
        #pragma unroll
        for (int u = 0; u < 4; ++u) {
            long r = i + u;
            float v = 0.f;
            if (r < W_OFF) { if (r < P_READ) v = b_read[r]; }
            else { long wr = r - W_OFF; if (wr < P_WRITE) v = b_write[wr]; }
            bias_rw[r] = v;
        }
    }
}

// ================= K2: gates GEMM + LSTM -> h_b [256][1024] bf16 =================
__global__ __launch_bounds__(64)
void gemm_gates(const __hip_bfloat16* __restrict__ x_b,
                const __hip_bfloat16* __restrict__ Wih_c,
                const float* __restrict__ bias_c,
                __hip_bfloat16* __restrict__ h_b)
{
    const int l = threadIdx.x;
    const int bn = blockIdx.x * 16;
    const int bm = blockIdx.y * 16;
    const int r = l & 15, q = l >> 4;
    const __hip_bfloat16* ap = x_b + (size_t)(bm + r) * INW + q * 8;
    const __hip_bfloat16* bi = Wih_c + (size_t)(bn + r) * INW + q * 8;
    const __hip_bfloat16* bg = bi + (size_t)1024 * INW;
    const __hip_bfloat16* bo = bi + (size_t)2048 * INW;
    f32x4 ai = {0.f,0.f,0.f,0.f}, ag = ai, ao = ai;
    #pragma unroll
    for (int k = 0; k < INW; k += 32) {
        bf16x8 a = *reinterpret_cast<const bf16x8*>(ap + k);
        ai = __builtin_amdgcn_mfma_f32_16x16x32_bf16(a, *reinterpret_cast<const bf16x8*>(bi + k), ai, 0, 0, 0);
        ag = __builtin_amdgcn_mfma_f32_16x16x32_bf16(a, *reinterpret_cast<const bf16x8*>(bg + k), ag, 0, 0, 0);
        ao = __builtin_amdgcn_mfma_f32_16x16x32_bf16(a, *reinterpret_cast<const bf16x8*>(bo + k), ao, 0, 0, 0);
    }
    const int j = bn + r;
    const float bii = bias_c[j], big = bias_c[1024 + j], bio = bias_c[2048 + j];
    #pragma unroll
    for (int jj = 0; jj < 4; ++jj) {
        int b = bm + q * 4 + jj;
        float c = sigmoidf(ai[jj] + bii) * tanhf(ag[jj] + big);
        h_b[(size_t)b * HH + j] = __float2bfloat16(sigmoidf(ao[jj] + bio) * tanhf(c));
    }
}

// ================= K3: dual GEMM (rpwp || out h-part) =================
__global__ __launch_bounds__(64)
void gemm_dual(const __hip_bfloat16* __restrict__ h_b,
               const __hip_bfloat16* __restrict__ Wrw_p,
               const __hip_bfloat16* __restrict__ Wo_b,
               const float* __restrict__ bias_rw, const float* __restrict__ b_out,
               float* __restrict__ rpwp, float* __restrict__ out)
{
    const int bid = blockIdx.x;
    const int lane = threadIdx.x;
    const int r = lane & 15, q = lane >> 4;
    int bm, bn, ldb;
    const __hip_bfloat16* B;
    if (bid < 1056) { int nt = bid % 66, mt = bid / 66; bm = mt * 16; bn = nt * 16; B = Wrw_p; ldb = HH; }
    else { int o = bid - 1056; int nt = o & 31, mt = o >> 5; bm = mt * 16; bn = nt * 16; B = Wo_b; ldb = 1280; }

    const __hip_bfloat16* ap = h_b + (size_t)(bm + r) * HH + q * 8;
    const __hip_bfloat16* bp = B + (size_t)(bn + r) * ldb + q * 8;
    f32x4 a0 = {0.f,0.f,0.f,0.f}, a1 = a0;
    #pragma unroll 8
    for (int k = 0; k < 512; k += 32) {
        a0 = __builtin_amdgcn_mfma_f32_16x16x32_bf16(
            *reinterpret_cast<const bf16x8*>(ap + k),
            *reinterpret_cast<const bf16x8*>(bp + k), a0, 0, 0, 0);
        a1 = __builtin_amdgcn_mfma_f32_16x16x32_bf16(
            *reinterpret_cast<const bf16x8*>(ap + 512 + k),
            *reinterpret_cast<const bf16x8*>(bp + 512 + k), a1, 0, 0, 0);
    }
    const int col = bn + r;
    if (bid < 1056) {
        const float bv = bias_rw[col];
        #pragma unroll
        for (int j = 0; j < 4; ++j) {
            int m = bm + q * 4 + j;
            rpwp[(size_t)m * RW_LD + col] = a0[j] + a1[j] + bv;
        }
    } else {
        const float bv = b_out[col];
        #pragma unroll
        for (int j = 0; j < 4; ++j) {
            int m = bm + q * 4 + j;
            out[(size_t)m * OUTW + col] = a0[j] + a1[j] + bv;
        }
    }
}

// ================= K4: tail — per-batch num GEMV + addressing + t12 GEMV + rv =================
// 256 blocks x 512 threads (8 waves). All global streams coalesced.
__device__ __forceinline__ void redpair_sum(float& a, float& b, volatile float* redA, volatile float* redB) {
    #pragma unroll
    for (int off = 32; off > 0; off >>= 1) { a += __shfl_down(a, off, 64); b += __shfl_down(b, off, 64); }
    int wid = threadIdx.x >> 6;
    __syncthreads();
    if ((threadIdx.x & 63) == 0) { redA[wid] = a; redB[wid] = b; }
    __syncthreads();
    a = redA[0]+redA[1]+redA[2]+redA[3]+redA[4]+redA[5]+redA[6]+redA[7];
    b = redB[0]+redB[1]+redB[2]+redB[3]+redB[4]+redB[5]+redB[6]+redB[7];
}
__device__ __forceinline__ void redpair_max(float& a, float& b, volatile float* redA, volatile float* redB) {
    #pragma unroll
    for (int off = 32; off > 0; off >>= 1) { a = fmaxf(a, __shfl_down(a, off, 64)); b = fmaxf(b, __shfl_down(b, off, 64)); }
    int wid = threadIdx.x >> 6;
    __syncthreads();
    if ((threadIdx.x & 63) == 0) { redA[wid] = a; redB[wid] = b; }
    __syncthreads();
    a = fmaxf(fmaxf(fmaxf(redA[0],redA[1]),fmaxf(redA[2],redA[3])),fmaxf(fmaxf(redA[4],redA[5]),fmaxf(redA[6],redA[7])));
    b = fmaxf(fmaxf(fmaxf(redB[0],redB[1]),fmaxf(redB[2],redB[3])),fmaxf(fmaxf(redB[4],redB[5]),fmaxf(redB[6],redB[7])));
}

__global__ __launch_bounds__(512)
void tail_kernel(const float* __restrict__ rpwp,
                 const __hip_bfloat16* __restrict__ mem_b,
                 __hip_bfloat16* __restrict__ rv_b)
{
    __shared__ float redA[8], redB[8];
    __shared__ __align__(16) float s_keyr[256], s_keyw[256];
    __shared__ float s_simr[512], s_simw[512], s_nrm[512];
    __shared__ float bufr[512], bufw[512];
    __shared__ float s_rw[512], s_pw[512];
    __shared__ float s_p1[8][256], s_p2[8][256];

    const int b = blockIdx.x;
    const int t = threadIdx.x;
    const int lane = t & 63;
    const int w = t >> 6;
    const float* pr  = rpwp + (size_t)b * RW_LD;
    const float* pw2 = pr + W_OFF;

    // ---- phase A: keys -> LDS, key norms ----
    float kv = (t < 256) ? pr[t] : pw2[t - 256];
    if (t < 256) s_keyr[t] = kv; else s_keyw[t - 256] = kv;
    {
        float vv = kv * kv;
        #pragma unroll
        for (int off = 32; off > 0; off >>= 1) vv += __shfl_down(vv, off, 64);
        if (lane == 0) redA[w] = vv;
    }
    __syncthreads();
    const float knr = fmaxf(sqrtf(redA[0]+redA[1]+redA[2]+redA[3]), 1e-8f);
    const float knw = fmaxf(sqrtf(redA[4]+redA[5]+redA[6]+redA[7]), 1e-8f);

    // ---- phase B: num GEMV (2 slots/step/wave) + on-the-fly mem norms ----
    {
        const int half = lane >> 5;      // which of the 2 slots
        const int l32 = lane & 31;       // position within a 512B row
        // keys for this lane's row-chunk, preloaded to registers (reused 32x)
        float kr8[8], kw8[8];
        #pragma unroll
        for (int e = 0; e < 8; ++e) { kr8[e] = s_keyr[l32 * 8 + e]; kw8[e] = s_keyw[l32 * 8 + e]; }
        for (int j = 0; j < 32; ++j) {
            int s = w * 64 + 2 * j + half;
            bf16x8 m8 = *reinterpret_cast<const bf16x8*>(mem_b + (size_t)s * WD + l32 * 8);
            float nr = 0.f, nw = 0.f, nn = 0.f;
            #pragma unroll
            for (int e = 0; e < 8; ++e) {
                float mv = b2f(m8[e]);
                nr += kr8[e] * mv; nw += kw8[e] * mv; nn += mv * mv;
            }
            #pragma unroll
            for (int off = 1; off < 32; off <<= 1) {
                nr += __shfl_xor(nr, off, 64);
                nw += __shfl_xor(nw, off, 64);
                nn += __shfl_xor(nn, off, 64);
            }
            if (l32 == 0) {
                s_simr[s] = nr; s_simw[s] = nw;
                s_nrm[s] = fmaxf(sqrtf(nn), 1e-8f);
            }
        }
    }
    __syncthreads();

    // ---- phase C: addressing (t = slot) ----
    float t3v;
    {
        // header params (broadcast reads)
        float beta_r  = softplusf(pr[WD]);
        float gate_r  = sigmoidf(pr[WD + 1]);
        float r0 = pr[WD+2], r1 = pr[WD+3], r2 = pr[WD+4];
        float rmx = fmaxf(r0, fmaxf(r1, r2));
        float re0 = expf(r0-rmx), re1 = expf(r1-rmx), re2 = expf(r2-rmx);
        float rinv = 1.f / (re0+re1+re2);
        float shr0 = re0*rinv, shr1 = re1*rinv, shr2 = re2*rinv;
        float gamma_r = 1.f + softplusf(pr[WD + 5]);

        float beta_w  = softplusf(pw2[WD]);
        float gate_w  = sigmoidf(pw2[WD + 1]);
        float w0 = pw2[WD+2], w1 = pw2[WD+3], w2 = pw2[WD+4];
        float wmx = fmaxf(w0, fmaxf(w1, w2));
        float we0 = expf(w0-wmx), we1 = expf(w1-wmx), we2 = expf(w2-wmx);
        float winv = 1.f / (we0+we1+we2);
        float shw0 = we0*winv, shw1 = we1*winv, shw2 = we2*winv;
        float gamma_w = 1.f + softplusf(pw2[WD + 5]);

        float ninv = 1.f / s_nrm[t];
        float sim_r = s_simr[t] * ninv / knr * beta_r;
        float sim_w = s_simw[t] * ninv / knw * beta_w;

        float mr = sim_r, mw = sim_w;
        redpair_max(mr, mw, redA, redB);
        float exr = expf(sim_r - mr), exw = expf(sim_w - mw);
        float sr = exr, sw = exw;
        redpair_sum(sr, sw, redA, redB);
        float cwr = exr / sr, cww = exw / sw;

        float onehot = (t == 0) ? 1.f : 0.f;
        float gwr = gate_r * cwr + (1.f - gate_r) * onehot;
        float gww = gate_w * cww + (1.f - gate_w) * onehot;
        __syncthreads();
        bufr[t] = gwr; bufw[t] = gww;
        __syncthreads();

        int tm = (t + SS - 1) & (SS - 1), tp = (t + 1) & (SS - 1);
        float swr = shr0 * bufr[tm] + shr1 * gwr + shr2 * bufr[tp];
        float sww = shw0 * bufw[tm] + shw1 * gww + shw2 * bufw[tp];

        float spr = powf(fmaxf(swr, 0.f), gamma_r), spw = powf(fmaxf(sww, 0.f), gamma_w);
        float ssr = spr, ssw = spw;
        redpair_sum(ssr, ssw, redA, redB);
        float rfin = spr / (ssr + 1e-6f);
        float wfin = spw / (ssw + 1e-6f);
        float prod = rfin * wfin;

        s_rw[t] = rfin; s_pw[t] = prod;
        float tp3 = prod, dmy = 0.f;
        redpair_sum(tp3, dmy, redA, redB);   // includes syncthreads -> s_rw/s_pw visible after
        t3v = tp3;
    }
    __syncthreads();

    // ---- phase D: t12 GEMV (row-broadcast) + rv epilogue ----
    {
        const int wcol = lane * 4;           // 4 w-columns per lane
        float a1_0=0.f,a1_1=0.f,a1_2=0.f,a1_3=0.f;
        float a2_0=0.f,a2_1=0.f,a2_2=0.f,a2_3=0.f;
        const int s0 = w * 64;
        for (int s = s0; s < s0 + 64; ++s) {
            bf16x4 m4 = *reinterpret_cast<const bf16x4*>(mem_b + (size_t)s * WD + wcol);
            float rw = s_rw[s], pwv = s_pw[s];
            float m0 = b2f(m4[0]), m1 = b2f(m4[1]), m2 = b2f(m4[2]), m3 = b2f(m4[3]);
            a1_0 += rw * m0; a1_1 += rw * m1; a1_2 += rw * m2; a1_3 += rw * m3;
            a2_0 += pwv * m0; a2_1 += pwv * m1; a2_2 += pwv * m2; a2_3 += pwv * m3;
        }
        s_p1[w][wcol] = a1_0; s_p1[w][wcol+1] = a1_1; s_p1[w][wcol+2] = a1_2; s_p1[w][wcol+3] = a1_3;
        s_p2[w][wcol] = a2_0; s_p2[w][wcol+1] = a2_1; s_p2[w][wcol+2] = a2_2; s_p2[w][wcol+3] = a2_3;
    }
    __syncthreads();
    if (t < 256) {
        float t1 = 0.f, t2 = 0.f;
        #pragma unroll
        for (int ww = 0; ww < 8; ++ww) { t1 += s_p1[ww][t]; t2 += s_p2[ww][t]; }
        float e = sigmoidf(pw2[P_READ + t]);
        float a = tanhf(pw2[P_READ + WD + t]);
        rv_b[(size_t)b * WD + t] = __float2bfloat16(t1 - e * t2 + a * t3v);
    }
}

// ================= K5: out += rv_b @ Wo_rv^T =================
__global__ __launch_bounds__(64)
void gemm_outrv(const __hip_bfloat16* __restrict__ rv_b,
                const __hip_bfloat16* __restrict__ Wo_b,
                float* __restrict__ out)
{
    const int l = threadIdx.x;
    const int bn = blockIdx.x * 16;   // out col
    const int bm = blockIdx.y * 16;   // batch
    const int r = l & 15, q = l >> 4;
    const __hip_bfloat16* ap = rv_b + (size_t)(bm + r) * WD + q * 8;
    const __hip_bfloat16* bp = Wo_b + (size_t)(bn + r) * 1280 + 1024 + q * 8;
    f32x4 acc = {0.f,0.f,0.f,0.f};
    #pragma unroll
    for (int k = 0; k < WD; k += 32)
        acc = __builtin_amdgcn_mfma_f32_16x16x32_bf16(
            *reinterpret_cast<const bf16x8*>(ap + k),
            *reinterpret_cast<const bf16x8*>(bp + k), acc, 0, 0, 0);
    const int col = bn + r;
    #pragma unroll
    for (int j = 0; j < 4; ++j) {
        int m = bm + q * 4 + j;
        out[(size_t)m * OUTW + col] += acc[j];
    }
}

// ---------------- host launcher ----------------
extern "C" void kernel_launch(void* const* d_in, const int* in_sizes, int n_in,
                              void* d_out, int out_size, void* d_ws, size_t ws_size,
                              hipStream_t stream)
{
    const float* x       = (const float*)d_in[0];
    const float* W_ih    = (const float*)d_in[1];
    const float* b_ih    = (const float*)d_in[2];
    const float* b_hh    = (const float*)d_in[4];
    const float* W_read  = (const float*)d_in[5];
    const float* b_read  = (const float*)d_in[6];
    const float* W_write = (const float*)d_in[7];
    const float* b_write = (const float*)d_in[8];
    const float* W_out   = (const float*)d_in[9];
    const float* b_out   = (const float*)d_in[10];
    const float* mem     = (const float*)d_in[11];

    float* ws = (float*)d_ws;
    float* rpwp     = ws;                 // 270336
    float* bias_c   = ws + 270336;        // 3072
    float* bias_rw  = ws + 273408;        // 1056
    __hip_bfloat16* bfb = (__hip_bfloat16*)(ws + 274464);
    __hip_bfloat16* x_b    = bfb;                 // 131072
    __hip_bfloat16* Wih_c  = bfb + 131072;        // 1572864
    __hip_bfloat16* Wrw_p  = bfb + 1703936;       // 1081344
    __hip_bfloat16* Wo_b   = bfb + 2785280;       // 655360
    __hip_bfloat16* mem_b  = bfb + 3440640;       // 131072
    __hip_bfloat16* h_b    = bfb + 3571712;       // 262144
    __hip_bfloat16* rv_b   = bfb + 3833856;       // 65536
    float* out = (float*)d_out;

    // K1: convert/pack + biases
    convert_all<<<NB_CVT, 256, 0, stream>>>(
        W_ih, b_ih, b_hh, W_read, b_read, W_write, b_write, W_out, x, mem,
        Wih_c, Wrw_p, Wo_b, x_b, mem_b, bias_c, bias_rw);
    // K2: gates GEMM + LSTM -> h_b
    gemm_gates<<<dim3(64, 16), 64, 0, stream>>>(x_b, Wih_c, bias_c, h_b);
    // K3: rpwp GEMM || out h-part GEMM
    gemm_dual<<<1568, 64, 0, stream>>>(h_b, Wrw_p, Wo_b, bias_rw, b_out, rpwp, out);
    // K4: per-batch tail (num + addressing + t12 + rv)
    tail_kernel<<<BB, 512, 0, stream>>>(rpwp, mem_b, rv_b);
    // K5: out += rv_b @ Wo_rv^T
    gemm_outrv<<<dim3(32, 16), 64, 0, stream>>>(rv_b, Wo_b, out);
}

// Round 11
// 70.907 us; speedup vs baseline: 1.0838x; 1.0838x over previous
//
#include <hip/hip_runtime.h>
#include <hip/hip_bf16.h>
#include <math.h>

// Problem constants
#define BB   256
#define INW  512
#define HH   1024
#define OUTW 512
#define SS   512
#define WD   256
#define P_READ  262
#define P_WRITE 774
#define RW_LD   1056   // 272 (read pad) + 784 (write pad)
#define W_OFF   272

typedef __attribute__((ext_vector_type(8))) short bf16x8;
typedef __attribute__((ext_vector_type(4))) float f32x4;

__device__ __forceinline__ float sigmoidf(float x) { return 1.f / (1.f + expf(-x)); }
__device__ __forceinline__ float softplusf(float x) { return (x > 20.f) ? x : log1pf(expf(x)); }
__device__ __forceinline__ unsigned short f2b(float f) {
    union { float f; unsigned u; } c; c.f = f;
    return (unsigned short)((c.u + 0x7FFFu + ((c.u >> 16) & 1u)) >> 16);
}
__device__ __forceinline__ void st_bf4(__hip_bfloat16* d, float a, float b, float c, float e) {
    ushort4 u; u.x = f2b(a); u.y = f2b(b); u.z = f2b(c); u.w = f2b(e);
    *reinterpret_cast<ushort4*>(d) = u;
}
__device__ __forceinline__ float wave_sum(float v) {
    #pragma unroll
    for (int off = 32; off > 0; off >>= 1) v += __shfl_down(v, off, 64);
    return v;
}

// conversion segment sizes (all multiples of 4)
#define N_WIH (3072*512)
#define N_WRW (RW_LD*1024)
#define N_WO  (512*1280)
#define N_X   (256*512)
#define N_MB  (512*256)
#define N_MT  (256*512)
#define N_BIA 3072
#define N_BRW RW_LD
#define N_TOT (N_WIH+N_WRW+N_WO+N_X+N_MB+N_MT+N_BIA+N_BRW)
#define NB_CVT ((N_TOT/4 + 255) / 256)

// ================= K1: convert/pack (4-wide) + mem norms + biases =================
__global__ __launch_bounds__(256)
void convert_all(const float* __restrict__ W_ih, const float* __restrict__ b_ih,
                 const float* __restrict__ b_hh,
                 const float* __restrict__ W_read, const float* __restrict__ b_read,
                 const float* __restrict__ W_write, const float* __restrict__ b_write,
                 const float* __restrict__ W_out, const float* __restrict__ x,
                 const float* __restrict__ mem,
                 __hip_bfloat16* __restrict__ Wih_c, __hip_bfloat16* __restrict__ Wrw_p,
                 __hip_bfloat16* __restrict__ Wo_b, __hip_bfloat16* __restrict__ x_b,
                 __hip_bfloat16* __restrict__ mem_b, __hip_bfloat16* __restrict__ memT_b,
                 float* __restrict__ bias_c, float* __restrict__ bias_rw,
                 float* __restrict__ mem_norm)
{
    if (blockIdx.x >= NB_CVT) {
        __shared__ float red[4];
        int s = blockIdx.x - NB_CVT;
        float v = mem[(size_t)s * WD + threadIdx.x];
        float vv = wave_sum(v * v);
        if ((threadIdx.x & 63) == 0) red[threadIdx.x >> 6] = vv;
        __syncthreads();
        if (threadIdx.x == 0)
            mem_norm[s] = fmaxf(sqrtf(red[0] + red[1] + red[2] + red[3]), 1e-8f);
        return;
    }
    long i = ((long)blockIdx.x * 256 + threadIdx.x) * 4;
    if (i >= N_TOT) return;
    if (i < N_WIH) {
        int r = (int)(i >> 9), c = (int)(i & 511);
        int sr = r < 1024 ? r : r + 1024;    // skip f-gate rows
        float4 v = *reinterpret_cast<const float4*>(W_ih + (size_t)sr * 768 + c);
        st_bf4(Wih_c + i, v.x, v.y, v.z, v.w);
        return;
    }
    i -= N_WIH;
    if (i < N_WRW) {
        int r = (int)(i >> 10), c = (int)(i & 1023);
        float4 v = make_float4(0.f, 0.f, 0.f, 0.f);
        if (r < W_OFF) { if (r < P_READ) v = *reinterpret_cast<const float4*>(W_read + (size_t)r * 1024 + c); }
        else { int wr = r - W_OFF; if (wr < P_WRITE) v = *reinterpret_cast<const float4*>(W_write + (size_t)wr * 1024 + c); }
        st_bf4(Wrw_p + i, v.x, v.y, v.z, v.w);
        return;
    }
    i -= N_WRW;
    if (i < N_WO) {
        float4 v = *reinterpret_cast<const float4*>(W_out + i);
        st_bf4(Wo_b + i, v.x, v.y, v.z, v.w);
        return;
    }
    i -= N_WO;
    if (i < N_X) {
        float4 v = *reinterpret_cast<const float4*>(x + i);
        st_bf4(x_b + i, v.x, v.y, v.z, v.w);
        return;
    }
    i -= N_X;
    if (i < N_MB) {
        float4 v = *reinterpret_cast<const float4*>(mem + i);
        st_bf4(mem_b + i, v.x, v.y, v.z, v.w);
        return;
    }
    i -= N_MB;
    if (i < N_MT) {   // transpose gather (L2/L3-resident source)
        int w = (int)(i >> 9), s = (int)(i & 511);
        st_bf4(memT_b + i, mem[(size_t)s * 256 + w], mem[(size_t)(s + 1) * 256 + w],
               mem[(size_t)(s + 2) * 256 + w], mem[(size_t)(s + 3) * 256 + w]);
        return;
    }
    i -= N_MT;
    if (i < N_BIA) {
        #pragma unroll
        for (int u = 0; u < 4; ++u) {
            long r = i + u;
            long sr = r < 1024 ? r : r + 1024;
            bias_c[r] = b_ih[sr] + b_hh[sr];
        }
        return;
    }
    i -= N_BIA;
    {
        #pragma unroll
        for (int u = 0; u < 4; ++u) {
            long r = i + u;
            float v = 0.f;
            if (r < W_OFF) { if (r < P_READ) v = b_read[r]; }
            else { long wr = r - W_OFF; if (wr < P_WRITE) v = b_write[wr]; }
            bias_rw[r] = v;
        }
    }
}

// ================= K2: gates GEMM + LSTM -> h_b [256][1024] bf16 =================
__global__ __launch_bounds__(64)
void gemm_gates(const __hip_bfloat16* __restrict__ x_b,
                const __hip_bfloat16* __restrict__ Wih_c,
                const float* __restrict__ bias_c,
                __hip_bfloat16* __restrict__ h_b)
{
    const int l = threadIdx.x;
    const int bn = blockIdx.x * 16;
    const int bm = blockIdx.y * 16;
    const int r = l & 15, q = l >> 4;
    const __hip_bfloat16* ap = x_b + (size_t)(bm + r) * INW + q * 8;
    const __hip_bfloat16* bi = Wih_c + (size_t)(bn + r) * INW + q * 8;
    const __hip_bfloat16* bg = bi + (size_t)1024 * INW;
    const __hip_bfloat16* bo = bi + (size_t)2048 * INW;
    f32x4 ai = {0.f,0.f,0.f,0.f}, ag = ai, ao = ai;
    #pragma unroll
    for (int k = 0; k < INW; k += 32) {
        bf16x8 a = *reinterpret_cast<const bf16x8*>(ap + k);
        ai = __builtin_amdgcn_mfma_f32_16x16x32_bf16(a, *reinterpret_cast<const bf16x8*>(bi + k), ai, 0, 0, 0);
        ag = __builtin_amdgcn_mfma_f32_16x16x32_bf16(a, *reinterpret_cast<const bf16x8*>(bg + k), ag, 0, 0, 0);
        ao = __builtin_amdgcn_mfma_f32_16x16x32_bf16(a, *reinterpret_cast<const bf16x8*>(bo + k), ao, 0, 0, 0);
    }
    const int j = bn + r;
    const float bii = bias_c[j], big = bias_c[1024 + j], bio = bias_c[2048 + j];
    #pragma unroll
    for (int jj = 0; jj < 4; ++jj) {
        int b = bm + q * 4 + jj;
        float c = sigmoidf(ai[jj] + bii) * tanhf(ag[jj] + big);
        h_b[(size_t)b * HH + j] = __float2bfloat16(sigmoidf(ao[jj] + bio) * tanhf(c));
    }
}

// ================= K3: dual GEMM (rpwp + interleaved keys harvest || out h-part) =================
__global__ __launch_bounds__(64)
void gemm_dual(const __hip_bfloat16* __restrict__ h_b,
               const __hip_bfloat16* __restrict__ Wrw_p,
               const __hip_bfloat16* __restrict__ Wo_b,
               const float* __restrict__ bias_rw, const float* __restrict__ b_out,
               float* __restrict__ rpwp, float* __restrict__ out,
               __hip_bfloat16* __restrict__ keys)
{
    const int bid = blockIdx.x;
    const int lane = threadIdx.x;
    const int r = lane & 15, q = lane >> 4;
    int bm, bn, ldb;
    const __hip_bfloat16* B;
    if (bid < 1056) { int nt = bid % 66, mt = bid / 66; bm = mt * 16; bn = nt * 16; B = Wrw_p; ldb = HH; }
    else { int o = bid - 1056; int nt = o & 31, mt = o >> 5; bm = mt * 16; bn = nt * 16; B = Wo_b; ldb = 1280; }

    const __hip_bfloat16* ap = h_b + (size_t)(bm + r) * HH + q * 8;
    const __hip_bfloat16* bp = B + (size_t)(bn + r) * ldb + q * 8;
    f32x4 a0 = {0.f,0.f,0.f,0.f}, a1 = a0;
    #pragma unroll 8
    for (int k = 0; k < 512; k += 32) {
        a0 = __builtin_amdgcn_mfma_f32_16x16x32_bf16(
            *reinterpret_cast<const bf16x8*>(ap + k),
            *reinterpret_cast<const bf16x8*>(bp + k), a0, 0, 0, 0);
        a1 = __builtin_amdgcn_mfma_f32_16x16x32_bf16(
            *reinterpret_cast<const bf16x8*>(ap + 512 + k),
            *reinterpret_cast<const bf16x8*>(bp + 512 + k), a1, 0, 0, 0);
    }
    const int col = bn + r;
    if (bid < 1056) {
        const float bv = bias_rw[col];
        #pragma unroll
        for (int j = 0; j < 4; ++j) {
            int m = bm + q * 4 + j;
            float v = a0[j] + a1[j] + bv;
            rpwp[(size_t)m * RW_LD + col] = v;
            // interleaved keys: row 2m = read key, row 2m+1 = write key
            if (col < WD)
                keys[(size_t)(2 * m) * WD + col] = __float2bfloat16(v);
            else if (col >= W_OFF && col < W_OFF + WD)
                keys[(size_t)(2 * m + 1) * WD + (col - W_OFF)] = __float2bfloat16(v);
        }
    } else {
        const float bv = b_out[col];
        #pragma unroll
        for (int j = 0; j < 4; ++j) {
            int m = bm + q * 4 + j;
            out[(size_t)m * OUTW + col] = a0[j] + a1[j] + bv;
        }
    }
}

// ================= K4: tail — per-batch MFMA num + addressing + MFMA t12 + rv + MFMA out_rv =================
// 256 blocks x 512 threads. All dot products via M-padded MFMA (rows >=2 clamped/garbage).
__device__ __forceinline__ void redpair_sum(float& a, float& b, volatile float* redA, volatile float* redB) {
    #pragma unroll
    for (int off = 32; off > 0; off >>= 1) { a += __shfl_down(a, off, 64); b += __shfl_down(b, off, 64); }
    int wid = threadIdx.x >> 6;
    __syncthreads();
    if ((threadIdx.x & 63) == 0) { redA[wid] = a; redB[wid] = b; }
    __syncthreads();
    a = redA[0]+redA[1]+redA[2]+redA[3]+redA[4]+redA[5]+redA[6]+redA[7];
    b = redB[0]+redB[1]+redB[2]+redB[3]+redB[4]+redB[5]+redB[6]+redB[7];
}
__device__ __forceinline__ void redpair_max(float& a, float& b, volatile float* redA, volatile float* redB) {
    #pragma unroll
    for (int off = 32; off > 0; off >>= 1) { a = fmaxf(a, __shfl_down(a, off, 64)); b = fmaxf(b, __shfl_down(b, off, 64)); }
    int wid = threadIdx.x >> 6;
    __syncthreads();
    if ((threadIdx.x & 63) == 0) { redA[wid] = a; redB[wid] = b; }
    __syncthreads();
    a = fmaxf(fmaxf(fmaxf(redA[0],redA[1]),fmaxf(redA[2],redA[3])),fmaxf(fmaxf(redA[4],redA[5]),fmaxf(redA[6],redA[7])));
    b = fmaxf(fmaxf(fmaxf(redB[0],redB[1]),fmaxf(redB[2],redB[3])),fmaxf(fmaxf(redB[4],redB[5]),fmaxf(redB[6],redB[7])));
}

__global__ __launch_bounds__(512)
void tail_kernel(const float* __restrict__ rpwp, const float* __restrict__ mem_norm,
                 const __hip_bfloat16* __restrict__ keys,
                 const __hip_bfloat16* __restrict__ mem_b,
                 const __hip_bfloat16* __restrict__ memT_b,
                 const __hip_bfloat16* __restrict__ Wo_b,
                 float* __restrict__ out)
{
    __shared__ float redA[8], redB[8];
    __shared__ float s_num[2][520];
    __shared__ __hip_bfloat16 s_a12[2][512];
    __shared__ float s_t12[2][264];
    __shared__ __hip_bfloat16 s_rv[264];
    __shared__ float bufr[512], bufw[512];

    const int b = blockIdx.x;
    const int t = threadIdx.x;
    const int lane = t & 63;
    const int w = t >> 6;
    const int r = lane & 15, q = lane >> 4;   // q in 0..3
    const float* pr  = rpwp + (size_t)b * RW_LD;
    const float* pw2 = pr + W_OFF;

    // ---- phase A: key norms ----
    {
        float kv = (t < 256) ? pr[t] : pw2[t - 256];
        float vv = kv * kv;
        #pragma unroll
        for (int off = 32; off > 0; off >>= 1) vv += __shfl_down(vv, off, 64);
        if (lane == 0) redA[w] = vv;
    }
    __syncthreads();
    const float knr = fmaxf(sqrtf(redA[0]+redA[1]+redA[2]+redA[3]), 1e-8f);
    const float knw = fmaxf(sqrtf(redA[4]+redA[5]+redA[6]+redA[7]), 1e-8f);
    __syncthreads();

    // ---- phase B: num via MFMA. A rows: 0=read key, 1=write key (r>=2 clamped) ----
    {
        const int ar = (r < 2) ? r : 0;
        const __hip_bfloat16* ap = keys + (size_t)(2 * b + ar) * WD + q * 8;
        bf16x8 afr[8];
        #pragma unroll
        for (int k8 = 0; k8 < 8; ++k8)
            afr[k8] = *reinterpret_cast<const bf16x8*>(ap + k8 * 32);
        #pragma unroll
        for (int i = 0; i < 4; ++i) {
            const int bn = (w + i * 8) * 16;
            const __hip_bfloat16* bp = mem_b + (size_t)(bn + r) * WD + q * 8;
            f32x4 acc = {0.f,0.f,0.f,0.f};
            #pragma unroll
            for (int k8 = 0; k8 < 8; ++k8)
                acc = __builtin_amdgcn_mfma_f32_16x16x32_bf16(
                    afr[k8], *reinterpret_cast<const bf16x8*>(bp + k8 * 32), acc, 0, 0, 0);
            if (q == 0) { s_num[0][bn + r] = acc[0]; s_num[1][bn + r] = acc[1]; }
        }
    }
    __syncthreads();

    // ---- phase C: addressing (t = slot) ----
    float t3v;
    {
        float beta_r  = softplusf(pr[WD]);
        float gate_r  = sigmoidf(pr[WD + 1]);
        float r0 = pr[WD+2], r1 = pr[WD+3], r2 = pr[WD+4];
        float rmx = fmaxf(r0, fmaxf(r1, r2));
        float re0 = expf(r0-rmx), re1 = expf(r1-rmx), re2 = expf(r2-rmx);
        float rinv = 1.f / (re0+re1+re2);
        float shr0 = re0*rinv, shr1 = re1*rinv, shr2 = re2*rinv;
        float gamma_r = 1.f + softplusf(pr[WD + 5]);

        float beta_w  = softplusf(pw2[WD]);
        float gate_w  = sigmoidf(pw2[WD + 1]);
        float w0 = pw2[WD+2], w1 = pw2[WD+3], w2 = pw2[WD+4];
        float wmx = fmaxf(w0, fmaxf(w1, w2));
        float we0 = expf(w0-wmx), we1 = expf(w1-wmx), we2 = expf(w2-wmx);
        float winv = 1.f / (we0+we1+we2);
        float shw0 = we0*winv, shw1 = we1*winv, shw2 = we2*winv;
        float gamma_w = 1.f + softplusf(pw2[WD + 5]);

        float ninv = 1.f / mem_norm[t];
        float sim_r = s_num[0][t] * ninv / knr * beta_r;
        float sim_w = s_num[1][t] * ninv / knw * beta_w;

        float mr = sim_r, mw = sim_w;
        redpair_max(mr, mw, redA, redB);
        float exr = expf(sim_r - mr), exw = expf(sim_w - mw);
        float sr = exr, sw = exw;
        redpair_sum(sr, sw, redA, redB);
        float cwr = exr / sr, cww = exw / sw;

        float onehot = (t == 0) ? 1.f : 0.f;
        float gwr = gate_r * cwr + (1.f - gate_r) * onehot;
        float gww = gate_w * cww + (1.f - gate_w) * onehot;
        __syncthreads();
        bufr[t] = gwr; bufw[t] = gww;
        __syncthreads();   // CRITICAL: cross-lane LDS visibility for neighbor reads

        int tm = (t + SS - 1) & (SS - 1), tp = (t + 1) & (SS - 1);
        float swr = shr0 * bufr[tm] + shr1 * gwr + shr2 * bufr[tp];
        float sww = shw0 * bufw[tm] + shw1 * gww + shw2 * bufw[tp];

        float spr = powf(fmaxf(swr, 0.f), gamma_r), spw = powf(fmaxf(sww, 0.f), gamma_w);
        float ssr = spr, ssw = spw;
        redpair_sum(ssr, ssw, redA, redB);
        float rfin = spr / (ssr + 1e-6f);
        float wfin = spw / (ssw + 1e-6f);
        float prod = rfin * wfin;

        s_a12[0][t] = __float2bfloat16(rfin);
        s_a12[1][t] = __float2bfloat16(prod);
        float tp3 = prod, dmy = 0.f;
        redpair_sum(tp3, dmy, redA, redB);
        t3v = tp3;
    }
    __syncthreads();

    // ---- phase D: t12 via MFMA. A rows: 0=read_w, 1=read_w*write_w (LDS, clamped) ----
    {
        const int ar = (r < 2) ? r : 0;
        const __hip_bfloat16* ap = &s_a12[ar][q * 8];
        #pragma unroll
        for (int i = 0; i < 2; ++i) {
            const int bn = (w + i * 8) * 16;
            const __hip_bfloat16* bp = memT_b + (size_t)(bn + r) * SS + q * 8;
            f32x4 acc = {0.f,0.f,0.f,0.f};
            #pragma unroll
            for (int k = 0; k < SS; k += 32)
                acc = __builtin_amdgcn_mfma_f32_16x16x32_bf16(
                    *reinterpret_cast<const bf16x8*>(ap + k),
                    *reinterpret_cast<const bf16x8*>(bp + k), acc, 0, 0, 0);
            if (q == 0) { s_t12[0][bn + r] = acc[0]; s_t12[1][bn + r] = acc[1]; }
        }
    }
    __syncthreads();

    // ---- phase E: rv = t1 - e*t2 + a*t3 ----
    if (t < 256) {
        float t1 = s_t12[0][t], t2 = s_t12[1][t];
        float e = sigmoidf(pw2[P_READ + t]);
        float a = tanhf(pw2[P_READ + WD + t]);
        s_rv[t] = __float2bfloat16(t1 - e * t2 + a * t3v);
    }
    __syncthreads();

    // ---- phase F: out[b] += rv @ Wo_rv^T via MFMA (A row 0 = rv broadcast) ----
    {
        const __hip_bfloat16* ap = &s_rv[q * 8];
        bf16x8 afr[8];
        #pragma unroll
        for (int k8 = 0; k8 < 8; ++k8)
            afr[k8] = *reinterpret_cast<const bf16x8*>(ap + k8 * 32);
        #pragma unroll
        for (int i = 0; i < 4; ++i) {
            const int bn = (w + i * 8) * 16;
            const __hip_bfloat16* bp = Wo_b + (size_t)(bn + r) * 1280 + 1024 + q * 8;
            f32x4 acc = {0.f,0.f,0.f,0.f};
            #pragma unroll
            for (int k8 = 0; k8 < 8; ++k8)
                acc = __builtin_amdgcn_mfma_f32_16x16x32_bf16(
                    afr[k8], *reinterpret_cast<const bf16x8*>(bp + k8 * 32), acc, 0, 0, 0);
            if (q == 0)
                out[(size_t)b * OUTW + bn + r] += acc[0];
        }
    }
}

// ---------------- host launcher ----------------
extern "C" void kernel_launch(void* const* d_in, const int* in_sizes, int n_in,
                              void* d_out, int out_size, void* d_ws, size_t ws_size,
                              hipStream_t stream)
{
    const float* x       = (const float*)d_in[0];
    const float* W_ih    = (const float*)d_in[1];
    const float* b_ih    = (const float*)d_in[2];
    const float* b_hh    = (const float*)d_in[4];
    const float* W_read  = (const float*)d_in[5];
    const float* b_read  = (const float*)d_in[6];
    const float* W_write = (const float*)d_in[7];
    const float* b_write = (const float*)d_in[8];
    const float* W_out   = (const float*)d_in[9];
    const float* b_out   = (const float*)d_in[10];
    const float* mem     = (const float*)d_in[11];

    float* ws = (float*)d_ws;
    float* rpwp     = ws;                 // 270336
    float* bias_c   = ws + 270336;        // 3072
    float* bias_rw  = ws + 273408;        // 1056
    float* mem_norm = ws + 274464;        // 512
    __hip_bfloat16* bfb = (__hip_bfloat16*)(ws + 274976);
    __hip_bfloat16* x_b    = bfb;                 // 131072
    __hip_bfloat16* Wih_c  = bfb + 131072;        // 1572864
    __hip_bfloat16* Wrw_p  = bfb + 1703936;       // 1081344
    __hip_bfloat16* Wo_b   = bfb + 2785280;       // 655360
    __hip_bfloat16* mem_b  = bfb + 3440640;       // 131072
    __hip_bfloat16* memT_b = bfb + 3571712;       // 131072
    __hip_bfloat16* h_b    = bfb + 3702784;       // 262144
    __hip_bfloat16* keys   = bfb + 3964928;       // 131072 (interleaved rows 2b/2b+1)
    float* out = (float*)d_out;

    // K1: convert/pack + mem norms + biases
    convert_all<<<NB_CVT + SS, 256, 0, stream>>>(
        W_ih, b_ih, b_hh, W_read, b_read, W_write, b_write, W_out, x, mem,
        Wih_c, Wrw_p, Wo_b, x_b, mem_b, memT_b, bias_c, bias_rw, mem_norm);
    // K2: gates GEMM + LSTM -> h_b
    gemm_gates<<<dim3(64, 16), 64, 0, stream>>>(x_b, Wih_c, bias_c, h_b);
    // K3: rpwp GEMM (+keys harvest) || out h-part GEMM
    gemm_dual<<<1568, 64, 0, stream>>>(h_b, Wrw_p, Wo_b, bias_rw, b_out, rpwp, out, keys);
    // K4: per-batch tail, all dots via M-padded MFMA
    tail_kernel<<<BB, 512, 0, stream>>>(rpwp, mem_norm, keys, mem_b, memT_b, Wo_b, out);
}